// Round 1
// baseline (203.040 us; speedup 1.0000x reference)
//
#include <hip/hip_runtime.h>

typedef __attribute__((ext_vector_type(4))) float f32x4;
typedef __attribute__((ext_vector_type(8))) short bf16x8;

__device__ __forceinline__ unsigned short f2bf(float f) {
  union { float f; unsigned int u; } v; v.f = f;
  unsigned int r = v.u + 0x7fffu + ((v.u >> 16) & 1u);
  return (unsigned short)(r >> 16);
}
__device__ __forceinline__ float bflo(unsigned int u) {
  union { unsigned int u; float f; } v; v.u = u << 16; return v.f;
}
__device__ __forceinline__ float bfhi(unsigned int u) {
  union { unsigned int u; float f; } v; v.u = u & 0xffff0000u; return v.f;
}

// ---------------------------------------------------------------------------
// prep_A: A_ws[b][n][k*512+m] = bf16(cheb[k][m][n] * att[b][m][n])
// grid (8 m-tiles, 8 n-tiles, 32 b), 256 threads. LDS transpose 64x64 per k.
// ---------------------------------------------------------------------------
__global__ __launch_bounds__(256) void prep_A_k(const float* __restrict__ cheb,
                                                const float* __restrict__ att,
                                                unsigned short* __restrict__ A_ws) {
  __shared__ float tile[64][68];
  const int m0 = blockIdx.x * 64, n0 = blockIdx.y * 64, b = blockIdx.z;
  const int tid = threadIdx.x;
  const int rm = tid >> 2;   // 0..63
  const int c4 = tid & 3;    // 0..3
  for (int k = 0; k < 3; ++k) {
    const float* cp = cheb + ((size_t)(k * 512 + m0 + rm)) * 512 + n0 + c4 * 16;
    const float* ap = att  + ((size_t)(b * 512 + m0 + rm)) * 512 + n0 + c4 * 16;
#pragma unroll
    for (int j = 0; j < 4; ++j) {
      float4 c = *(const float4*)(cp + j * 4);
      float4 a = *(const float4*)(ap + j * 4);
      float4 p; p.x = c.x * a.x; p.y = c.y * a.y; p.z = c.z * a.z; p.w = c.w * a.w;
      *(float4*)&tile[rm][c4 * 16 + j * 4] = p;
    }
    __syncthreads();
    unsigned int pk[8];
#pragma unroll
    for (int i = 0; i < 8; ++i) {
      float v0 = tile[c4 * 16 + 2 * i][rm];
      float v1 = tile[c4 * 16 + 2 * i + 1][rm];
      pk[i] = (unsigned int)f2bf(v0) | ((unsigned int)f2bf(v1) << 16);
    }
    unsigned short* op = A_ws + ((size_t)(b * 512 + n0 + rm)) * 1536 + k * 512 + m0 + c4 * 16;
    uint4 w0; w0.x = pk[0]; w0.y = pk[1]; w0.z = pk[2]; w0.w = pk[3];
    uint4 w1; w1.x = pk[4]; w1.y = pk[5]; w1.z = pk[6]; w1.w = pk[7];
    ((uint4*)op)[0] = w0;
    ((uint4*)op)[1] = w1;
    __syncthreads();
  }
}

// ---------------------------------------------------------------------------
// prep_U: U_ws[b][k][o*12+t][m] = bf16( sum_f x[b,m,f,t] * Theta[k,f,o] )
// grid (32 m-tiles of 16, 32 b), 256 threads = 16 m x 16 o-blocks(4 o each).
// ---------------------------------------------------------------------------
__global__ __launch_bounds__(256) void prep_U_k(const float* __restrict__ x,
                                                const float* __restrict__ Theta,
                                                unsigned short* __restrict__ U_ws) {
  __shared__ unsigned short xt[16 * 772];      // [m][ft], ft stride padded 768->772
  __shared__ unsigned short tht[3 * 64 * 64];  // linear bf16 copy of Theta
  const int m0 = blockIdx.x * 16, b = blockIdx.y;
  const int tid = threadIdx.x;
  const float* xb = x + ((size_t)(b * 512 + m0)) * 768;
  for (int i = tid; i < 3072; i += 256) {  // 16*768 floats as float4
    int m = i / 192, cc = i % 192;
    float4 v = *(const float4*)(xb + (size_t)m * 768 + cc * 4);
    unsigned int lo = (unsigned int)f2bf(v.x) | ((unsigned int)f2bf(v.y) << 16);
    unsigned int hi = (unsigned int)f2bf(v.z) | ((unsigned int)f2bf(v.w) << 16);
    uint2 pk; pk.x = lo; pk.y = hi;
    *(uint2*)&xt[m * 772 + cc * 4] = pk;
  }
  for (int i = tid; i < 3072; i += 256) {  // 12288 floats as float4
    float4 v = *(const float4*)(Theta + (size_t)i * 4);
    unsigned int lo = (unsigned int)f2bf(v.x) | ((unsigned int)f2bf(v.y) << 16);
    unsigned int hi = (unsigned int)f2bf(v.z) | ((unsigned int)f2bf(v.w) << 16);
    uint2 pk; pk.x = lo; pk.y = hi;
    *(uint2*)&tht[i * 4] = pk;
  }
  __syncthreads();
  const int ml = tid & 15;
  const int ob = tid >> 4;  // o0 = ob*4
  const unsigned short* xrow = &xt[ml * 772];
  for (int k = 0; k < 3; ++k) {
    float acc[4][12];
#pragma unroll
    for (int oo = 0; oo < 4; ++oo)
#pragma unroll
      for (int t = 0; t < 12; ++t) acc[oo][t] = 0.f;
    const unsigned short* thk = &tht[k * 4096 + ob * 4];
    for (int f = 0; f < 64; ++f) {
      uint2 xa = *(const uint2*)(xrow + f * 12);
      uint2 xm = *(const uint2*)(xrow + f * 12 + 4);
      uint2 xc = *(const uint2*)(xrow + f * 12 + 8);
      float xf[12];
      xf[0] = bflo(xa.x);  xf[1] = bfhi(xa.x);  xf[2] = bflo(xa.y);  xf[3] = bfhi(xa.y);
      xf[4] = bflo(xm.x);  xf[5] = bfhi(xm.x);  xf[6] = bflo(xm.y);  xf[7] = bfhi(xm.y);
      xf[8] = bflo(xc.x);  xf[9] = bfhi(xc.x);  xf[10] = bflo(xc.y); xf[11] = bfhi(xc.y);
      uint2 th = *(const uint2*)(thk + f * 64);
      float tf[4] = {bflo(th.x), bfhi(th.x), bflo(th.y), bfhi(th.y)};
#pragma unroll
      for (int oo = 0; oo < 4; ++oo)
#pragma unroll
        for (int t = 0; t < 12; ++t) acc[oo][t] += tf[oo] * xf[t];
    }
    size_t base = (((size_t)b * 3 + k) * 768) * 512 + m0 + ml;
#pragma unroll
    for (int oo = 0; oo < 4; ++oo) {
      int o = ob * 4 + oo;
#pragma unroll
      for (int t = 0; t < 12; ++t)
        U_ws[base + (size_t)(o * 12 + t) * 512] = f2bf(acc[oo][t]);
    }
  }
}

// ---------------------------------------------------------------------------
// gemm_k: out[b][n][ot] = relu( sum_{km=0..1535} A_ws[b][n][km] * U_ws[b][k][ot][m] )
// 128x128 tile, BK=64, 4 waves (2x2), mfma_f32_16x16x32_bf16.
// Staging: swizzled GLOBAL source -> linear LDS write; XOR-swizzled ds_read_b128.
// grid (6 ot-tiles, 4 n-tiles, 32 b), 256 threads.
// ---------------------------------------------------------------------------
__global__ __launch_bounds__(256) void gemm_k(const unsigned short* __restrict__ A_ws,
                                              const unsigned short* __restrict__ U_ws,
                                              float* __restrict__ out) {
  __shared__ unsigned short At[128 * 64];
  __shared__ unsigned short Bt[128 * 64];
  const int otb = blockIdx.x * 128, nb = blockIdx.y * 128, b = blockIdx.z;
  const int tid = threadIdx.x;
  const int lane = tid & 63, w = tid >> 6;
  const int wr = w >> 1, wc = w & 1;
  const int rl = lane >> 3;  // 0..7, == (row & 7) since rows step by 8
  const int g = lane & 7;    // granule 0..7 (16B units within 128B row)
  const int q = lane >> 4;   // 0..3
  const int c = lane & 15;   // 0..15
  f32x4 acc[4][4] = {};

  const int rA = w * 32 + rl;                 // staged row base (+ i*8)
  const int gs = ((g ^ rl) << 3);             // pre-swizzled source granule (elements)
  const unsigned short* aBase = A_ws + ((size_t)(b * 512 + nb + rA)) * 1536 + gs;

  for (int kt = 0; kt < 24; ++kt) {
    const int k = kt >> 3;
    const int m0k = (kt & 7) << 6;
    bf16x8 av[4], bv[4];
#pragma unroll
    for (int i = 0; i < 4; ++i) {
      av[i] = *(const bf16x8*)(aBase + (size_t)(i * 8) * 1536 + kt * 64);
      const unsigned short* up =
          U_ws + ((size_t)((b * 3 + k) * 768 + otb + rA + i * 8)) * 512 + m0k + gs;
      bv[i] = *(const bf16x8*)up;
    }
    __syncthreads();  // all waves done reading prev tile
#pragma unroll
    for (int i = 0; i < 4; ++i) {   // linear LDS writes (conflict-free)
      *(bf16x8*)&At[(rA + i * 8) * 64 + (g << 3)] = av[i];
      *(bf16x8*)&Bt[(rA + i * 8) * 64 + (g << 3)] = bv[i];
    }
    __syncthreads();
#pragma unroll
    for (int h = 0; h < 2; ++h) {
      bf16x8 af[4], bfv[4];
#pragma unroll
      for (int mi = 0; mi < 4; ++mi) {
        int row = wr * 64 + mi * 16 + c;
        af[mi] = *(const bf16x8*)&At[row * 64 + (((h * 4 + q) ^ (row & 7)) << 3)];
      }
#pragma unroll
      for (int ni = 0; ni < 4; ++ni) {
        int row = wc * 64 + ni * 16 + c;
        bfv[ni] = *(const bf16x8*)&Bt[row * 64 + (((h * 4 + q) ^ (row & 7)) << 3)];
      }
#pragma unroll
      for (int mi = 0; mi < 4; ++mi)
#pragma unroll
        for (int ni = 0; ni < 4; ++ni)
          acc[mi][ni] = __builtin_amdgcn_mfma_f32_16x16x32_bf16(af[mi], bfv[ni], acc[mi][ni], 0, 0, 0);
    }
  }
  // epilogue: D row = 4*q + r, col = c ; relu + store fp32
#pragma unroll
  for (int mi = 0; mi < 4; ++mi) {
#pragma unroll
    for (int r = 0; r < 4; ++r) {
      int n = nb + wr * 64 + mi * 16 + q * 4 + r;
      float* orow = out + ((size_t)(b * 512 + n)) * 768 + otb + wc * 64 + c;
#pragma unroll
      for (int ni = 0; ni < 4; ++ni)
        orow[ni * 16] = fmaxf(acc[mi][ni][r], 0.f);
    }
  }
}

// ---------------------------------------------------------------------------
// Fallback (exact fp32, no workspace): grid (512 n, 32 b), 256 threads.
// ---------------------------------------------------------------------------
__global__ __launch_bounds__(256) void fallback_k(const float* __restrict__ x,
                                                  const float* __restrict__ cheb,
                                                  const float* __restrict__ att,
                                                  const float* __restrict__ Theta,
                                                  float* __restrict__ out) {
  __shared__ float wsm[3][512];
  __shared__ float z[3][768];
  const int n = blockIdx.x, b = blockIdx.y;
  const int tid = threadIdx.x;
  for (int i = tid; i < 1536; i += 256) {
    int k = i >> 9, m = i & 511;
    wsm[k][m] = cheb[((size_t)(k * 512 + m)) * 512 + n] * att[((size_t)(b * 512 + m)) * 512 + n];
  }
  __syncthreads();
  float a0[3] = {0.f, 0.f, 0.f}, a1[3] = {0.f, 0.f, 0.f}, a2[3] = {0.f, 0.f, 0.f};
  const float* xb = x + (size_t)b * 512 * 768;
  for (int m = 0; m < 512; ++m) {
    float w0 = wsm[0][m], w1 = wsm[1][m], w2 = wsm[2][m];
    float x0 = xb[(size_t)m * 768 + tid];
    float x1 = xb[(size_t)m * 768 + tid + 256];
    float x2 = xb[(size_t)m * 768 + tid + 512];
    a0[0] += w0 * x0; a0[1] += w1 * x0; a0[2] += w2 * x0;
    a1[0] += w0 * x1; a1[1] += w1 * x1; a1[2] += w2 * x1;
    a2[0] += w0 * x2; a2[1] += w1 * x2; a2[2] += w2 * x2;
  }
#pragma unroll
  for (int k = 0; k < 3; ++k) {
    z[k][tid] = a0[k]; z[k][tid + 256] = a1[k]; z[k][tid + 512] = a2[k];
  }
  __syncthreads();
#pragma unroll
  for (int j = 0; j < 3; ++j) {
    int ot = tid + j * 256;
    int o = ot / 12, t = ot - o * 12;
    float s = 0.f;
    for (int k = 0; k < 3; ++k)
#pragma unroll
      for (int f = 0; f < 64; ++f)
        s += z[k][f * 12 + t] * Theta[((size_t)(k * 64 + f)) * 64 + o];
    out[((size_t)(b * 512 + n)) * 768 + ot] = fmaxf(s, 0.f);
  }
}

extern "C" void kernel_launch(void* const* d_in, const int* in_sizes, int n_in,
                              void* d_out, int out_size, void* d_ws, size_t ws_size,
                              hipStream_t stream) {
  const float* x     = (const float*)d_in[0];  // (32,512,64,12)
  const float* cheb  = (const float*)d_in[1];  // (3,512,512)
  const float* att   = (const float*)d_in[2];  // (32,512,512)
  const float* Theta = (const float*)d_in[3];  // (3,64,64)
  float* out = (float*)d_out;                  // (32,512,64,12)

  const size_t needA = (size_t)32 * 512 * 1536 * 2;       // 50,331,648
  const size_t needU = (size_t)32 * 3 * 768 * 512 * 2;    // 75,497,472

  if (ws_size >= needA + needU) {
    unsigned short* A_ws = (unsigned short*)d_ws;
    unsigned short* U_ws = (unsigned short*)((char*)d_ws + needA);
    prep_A_k<<<dim3(8, 8, 32), 256, 0, stream>>>(cheb, att, A_ws);
    prep_U_k<<<dim3(32, 32), 256, 0, stream>>>(x, Theta, U_ws);
    gemm_k<<<dim3(6, 4, 32), 256, 0, stream>>>(A_ws, U_ws, out);
  } else {
    fallback_k<<<dim3(512, 32), 256, 0, stream>>>(x, cheb, att, Theta, out);
  }
}

// Round 2
// 153.112 us; speedup vs baseline: 1.3261x; 1.3261x over previous
//
#include <hip/hip_runtime.h>

typedef __attribute__((ext_vector_type(4))) float f32x4;
typedef __attribute__((ext_vector_type(8))) short bf16x8;

__device__ __forceinline__ unsigned short f2bf(float f) {
  union { float f; unsigned int u; } v; v.f = f;
  unsigned int r = v.u + 0x7fffu + ((v.u >> 16) & 1u);
  return (unsigned short)(r >> 16);
}
__device__ __forceinline__ float bflo(unsigned int u) {
  union { unsigned int u; float f; } v; v.u = u << 16; return v.f;
}
__device__ __forceinline__ float bfhi(unsigned int u) {
  union { unsigned int u; float f; } v; v.u = u & 0xffff0000u; return v.f;
}

// ---------------------------------------------------------------------------
// prep_A: A_ws[b][n][k*512+m] = bf16(cheb[k][m][n] * att[b][m][n])
// grid (8 m-tiles, 8 n-tiles, 32 b), 256 threads. LDS transpose 64x64 per k.
// ---------------------------------------------------------------------------
__global__ __launch_bounds__(256) void prep_A_k(const float* __restrict__ cheb,
                                                const float* __restrict__ att,
                                                unsigned short* __restrict__ A_ws) {
  __shared__ float tile[64][68];
  const int m0 = blockIdx.x * 64, n0 = blockIdx.y * 64, b = blockIdx.z;
  const int tid = threadIdx.x;
  const int rm = tid >> 2;   // 0..63
  const int c4 = tid & 3;    // 0..3
  for (int k = 0; k < 3; ++k) {
    const float* cp = cheb + ((size_t)(k * 512 + m0 + rm)) * 512 + n0 + c4 * 16;
    const float* ap = att  + ((size_t)(b * 512 + m0 + rm)) * 512 + n0 + c4 * 16;
#pragma unroll
    for (int j = 0; j < 4; ++j) {
      float4 c = *(const float4*)(cp + j * 4);
      float4 a = *(const float4*)(ap + j * 4);
      float4 p; p.x = c.x * a.x; p.y = c.y * a.y; p.z = c.z * a.z; p.w = c.w * a.w;
      *(float4*)&tile[rm][c4 * 16 + j * 4] = p;
    }
    __syncthreads();
    unsigned int pk[8];
#pragma unroll
    for (int i = 0; i < 8; ++i) {
      float v0 = tile[c4 * 16 + 2 * i][rm];
      float v1 = tile[c4 * 16 + 2 * i + 1][rm];
      pk[i] = (unsigned int)f2bf(v0) | ((unsigned int)f2bf(v1) << 16);
    }
    unsigned short* op = A_ws + ((size_t)(b * 512 + n0 + rm)) * 1536 + k * 512 + m0 + c4 * 16;
    uint4 w0; w0.x = pk[0]; w0.y = pk[1]; w0.z = pk[2]; w0.w = pk[3];
    uint4 w1; w1.x = pk[4]; w1.y = pk[5]; w1.z = pk[6]; w1.w = pk[7];
    ((uint4*)op)[0] = w0;
    ((uint4*)op)[1] = w1;
    __syncthreads();
  }
}

// ---------------------------------------------------------------------------
// prep_U_mfma: U_ws[b][k][o*12+t][m] = bf16( sum_f x[b,m,f,t] * Theta[k,f,o] )
// Per (b,t): C[o,m] = Theta_k^T[o,f] . X[f,m]  via mfma_f32_16x16x32_bf16.
// Block = (16-m tile, b). LDS: Xl[t][m][f] (24KB) + Tt[k][o][f] (24KB), both
// XOR-swizzled (granule ^= row&7) for conflict-free b128 fragment reads.
// Barrier-free (t,k) main loop; A-fragments hoisted to registers.
// grid (32 m-tiles, 32 b), 256 threads (4 waves; wave = 16 o-rows).
// ---------------------------------------------------------------------------
__global__ __launch_bounds__(256) void prep_U_mfma(const float* __restrict__ x,
                                                   const float* __restrict__ Theta,
                                                   unsigned short* __restrict__ U_ws) {
  __shared__ unsigned short Xl[12 * 16 * 64];  // [t][m][f] swizzled, 24KB
  __shared__ unsigned short Tt[3 * 64 * 64];   // [k][o][f] swizzled, 24KB
  const int m0 = blockIdx.x * 16, b = blockIdx.y;
  const int tid = threadIdx.x;
  const int lane = tid & 63, w = tid >> 6;
  const int c = lane & 15, q = lane >> 4;

  // ---- stage Xl: x[b, m0..m0+15, :, :] = 12288 floats, coalesced float4 ----
  const float* xb = x + ((size_t)(b * 512 + m0)) * 768;
#pragma unroll
  for (int j = 0; j < 12; ++j) {
    int i = tid + j * 256;              // float4 index 0..3071
    int m = i / 192, r = i - m * 192;   // 192 float4 per m-row
    float4 v = *(const float4*)(xb + (size_t)m * 768 + r * 4);
    float vv[4] = {v.x, v.y, v.z, v.w};
#pragma unroll
    for (int jj = 0; jj < 4; ++jj) {
      int e = r * 4 + jj;               // element = f*12 + t
      int f = e / 12, t = e - f * 12;
      int byte = t * 2048 + m * 128 + ((((f >> 3) ^ (m & 7)) << 4) | ((f & 7) << 1));
      *(unsigned short*)((char*)Xl + byte) = f2bf(vv[jj]);
    }
  }
  // ---- stage Tt: Tt[k][o][f] = Theta[k][f][o], 3072 float4 ----
#pragma unroll
  for (int j = 0; j < 12; ++j) {
    int i = tid + j * 256;              // 0..3071
    int k = i >> 10, rr = i & 1023;
    int f = rr >> 4, o0 = (rr & 15) << 2;
    float4 v = *(const float4*)(Theta + ((size_t)(k * 64 + f)) * 64 + o0);
    float vv[4] = {v.x, v.y, v.z, v.w};
#pragma unroll
    for (int jj = 0; jj < 4; ++jj) {
      int o = o0 + jj;
      int byte = k * 8192 + o * 128 + ((((f >> 3) ^ (o & 7)) << 4) | ((f & 7) << 1));
      *(unsigned short*)((char*)Tt + byte) = f2bf(vv[jj]);
    }
  }
  __syncthreads();

  // ---- hoist A-fragments (Theta^T rows w*16+c, k-granule q / q+4) ----
  bf16x8 afr[3][2];
#pragma unroll
  for (int k = 0; k < 3; ++k)
#pragma unroll
    for (int h = 0; h < 2; ++h) {
      int g = h * 4 + q;
      afr[k][h] = *(const bf16x8*)((char*)Tt +
                    k * 8192 + (w * 16 + c) * 128 + (((g ^ (c & 7)) << 4)));
    }

  // ---- main loop: per t, 2 b128 B-frag reads + 6 MFMA + 12 stores ----
  const size_t ub0 = ((size_t)(b * 3)) * 768 * 512 + m0 + c;
  for (int t = 0; t < 12; ++t) {
    bf16x8 bfr[2];
#pragma unroll
    for (int h = 0; h < 2; ++h) {
      int g = h * 4 + q;
      bfr[h] = *(const bf16x8*)((char*)Xl + t * 2048 + c * 128 + (((g ^ (c & 7)) << 4)));
    }
#pragma unroll
    for (int k = 0; k < 3; ++k) {
      f32x4 acc = {0.f, 0.f, 0.f, 0.f};
      acc = __builtin_amdgcn_mfma_f32_16x16x32_bf16(afr[k][0], bfr[0], acc, 0, 0, 0);
      acc = __builtin_amdgcn_mfma_f32_16x16x32_bf16(afr[k][1], bfr[1], acc, 0, 0, 0);
      size_t base = ub0 + (size_t)k * 768 * 512 + (size_t)t * 512;
#pragma unroll
      for (int r = 0; r < 4; ++r) {
        int o = w * 16 + q * 4 + r;
        U_ws[base + (size_t)o * 12 * 512] = f2bf(acc[r]);
      }
    }
  }
}

// ---------------------------------------------------------------------------
// gemm_k: out[b][n][ot] = relu( sum_{km=0..1535} A_ws[b][n][km] * U_ws[b][k][ot][m] )
// 128x128 tile, BK=64, 4 waves (2x2), mfma_f32_16x16x32_bf16.
// grid (6 ot-tiles, 4 n-tiles, 32 b), 256 threads.
// ---------------------------------------------------------------------------
__global__ __launch_bounds__(256) void gemm_k(const unsigned short* __restrict__ A_ws,
                                              const unsigned short* __restrict__ U_ws,
                                              float* __restrict__ out) {
  __shared__ unsigned short At[128 * 64];
  __shared__ unsigned short Bt[128 * 64];
  const int otb = blockIdx.x * 128, nb = blockIdx.y * 128, b = blockIdx.z;
  const int tid = threadIdx.x;
  const int lane = tid & 63, w = tid >> 6;
  const int wr = w >> 1, wc = w & 1;
  const int rl = lane >> 3;  // 0..7
  const int g = lane & 7;    // granule
  const int q = lane >> 4;   // 0..3
  const int c = lane & 15;   // 0..15
  f32x4 acc[4][4] = {};

  const int rA = w * 32 + rl;
  const int gs = ((g ^ rl) << 3);
  const unsigned short* aBase = A_ws + ((size_t)(b * 512 + nb + rA)) * 1536 + gs;

  for (int kt = 0; kt < 24; ++kt) {
    const int k = kt >> 3;
    const int m0k = (kt & 7) << 6;
    bf16x8 av[4], bv[4];
#pragma unroll
    for (int i = 0; i < 4; ++i) {
      av[i] = *(const bf16x8*)(aBase + (size_t)(i * 8) * 1536 + kt * 64);
      const unsigned short* up =
          U_ws + ((size_t)((b * 3 + k) * 768 + otb + rA + i * 8)) * 512 + m0k + gs;
      bv[i] = *(const bf16x8*)up;
    }
    __syncthreads();
#pragma unroll
    for (int i = 0; i < 4; ++i) {
      *(bf16x8*)&At[(rA + i * 8) * 64 + (g << 3)] = av[i];
      *(bf16x8*)&Bt[(rA + i * 8) * 64 + (g << 3)] = bv[i];
    }
    __syncthreads();
#pragma unroll
    for (int h = 0; h < 2; ++h) {
      bf16x8 af[4], bfv[4];
#pragma unroll
      for (int mi = 0; mi < 4; ++mi) {
        int row = wr * 64 + mi * 16 + c;
        af[mi] = *(const bf16x8*)&At[row * 64 + (((h * 4 + q) ^ (row & 7)) << 3)];
      }
#pragma unroll
      for (int ni = 0; ni < 4; ++ni) {
        int row = wc * 64 + ni * 16 + c;
        bfv[ni] = *(const bf16x8*)&Bt[row * 64 + (((h * 4 + q) ^ (row & 7)) << 3)];
      }
#pragma unroll
      for (int mi = 0; mi < 4; ++mi)
#pragma unroll
        for (int ni = 0; ni < 4; ++ni)
          acc[mi][ni] = __builtin_amdgcn_mfma_f32_16x16x32_bf16(af[mi], bfv[ni], acc[mi][ni], 0, 0, 0);
    }
  }
#pragma unroll
  for (int mi = 0; mi < 4; ++mi) {
#pragma unroll
    for (int r = 0; r < 4; ++r) {
      int n = nb + wr * 64 + mi * 16 + q * 4 + r;
      float* orow = out + ((size_t)(b * 512 + n)) * 768 + otb + wc * 64 + c;
#pragma unroll
      for (int ni = 0; ni < 4; ++ni)
        orow[ni * 16] = fmaxf(acc[mi][ni][r], 0.f);
    }
  }
}

// ---------------------------------------------------------------------------
// Fallback (exact fp32, no workspace): grid (512 n, 32 b), 256 threads.
// ---------------------------------------------------------------------------
__global__ __launch_bounds__(256) void fallback_k(const float* __restrict__ x,
                                                  const float* __restrict__ cheb,
                                                  const float* __restrict__ att,
                                                  const float* __restrict__ Theta,
                                                  float* __restrict__ out) {
  __shared__ float wsm[3][512];
  __shared__ float z[3][768];
  const int n = blockIdx.x, b = blockIdx.y;
  const int tid = threadIdx.x;
  for (int i = tid; i < 1536; i += 256) {
    int k = i >> 9, m = i & 511;
    wsm[k][m] = cheb[((size_t)(k * 512 + m)) * 512 + n] * att[((size_t)(b * 512 + m)) * 512 + n];
  }
  __syncthreads();
  float a0[3] = {0.f, 0.f, 0.f}, a1[3] = {0.f, 0.f, 0.f}, a2[3] = {0.f, 0.f, 0.f};
  const float* xb = x + (size_t)b * 512 * 768;
  for (int m = 0; m < 512; ++m) {
    float w0 = wsm[0][m], w1 = wsm[1][m], w2 = wsm[2][m];
    float x0 = xb[(size_t)m * 768 + tid];
    float x1 = xb[(size_t)m * 768 + tid + 256];
    float x2 = xb[(size_t)m * 768 + tid + 512];
    a0[0] += w0 * x0; a0[1] += w1 * x0; a0[2] += w2 * x0;
    a1[0] += w0 * x1; a1[1] += w1 * x1; a1[2] += w2 * x1;
    a2[0] += w0 * x2; a2[1] += w1 * x2; a2[2] += w2 * x2;
  }
#pragma unroll
  for (int k = 0; k < 3; ++k) {
    z[k][tid] = a0[k]; z[k][tid + 256] = a1[k]; z[k][tid + 512] = a2[k];
  }
  __syncthreads();
#pragma unroll
  for (int j = 0; j < 3; ++j) {
    int ot = tid + j * 256;
    int o = ot / 12, t = ot - o * 12;
    float s = 0.f;
    for (int k = 0; k < 3; ++k)
#pragma unroll
      for (int f = 0; f < 64; ++f)
        s += z[k][f * 12 + t] * Theta[((size_t)(k * 64 + f)) * 64 + o];
    out[((size_t)(b * 512 + n)) * 768 + ot] = fmaxf(s, 0.f);
  }
}

extern "C" void kernel_launch(void* const* d_in, const int* in_sizes, int n_in,
                              void* d_out, int out_size, void* d_ws, size_t ws_size,
                              hipStream_t stream) {
  const float* x     = (const float*)d_in[0];  // (32,512,64,12)
  const float* cheb  = (const float*)d_in[1];  // (3,512,512)
  const float* att   = (const float*)d_in[2];  // (32,512,512)
  const float* Theta = (const float*)d_in[3];  // (3,64,64)
  float* out = (float*)d_out;                  // (32,512,64,12)

  const size_t needA = (size_t)32 * 512 * 1536 * 2;       // 50,331,648
  const size_t needU = (size_t)32 * 3 * 768 * 512 * 2;    // 75,497,472

  if (ws_size >= needA + needU) {
    unsigned short* A_ws = (unsigned short*)d_ws;
    unsigned short* U_ws = (unsigned short*)((char*)d_ws + needA);
    prep_A_k<<<dim3(8, 8, 32), 256, 0, stream>>>(cheb, att, A_ws);
    prep_U_mfma<<<dim3(32, 32), 256, 0, stream>>>(x, Theta, U_ws);
    gemm_k<<<dim3(6, 4, 32), 256, 0, stream>>>(A_ws, U_ws, out);
  } else {
    fallback_k<<<dim3(512, 32), 256, 0, stream>>>(x, cheb, att, Theta, out);
  }
}

// Round 3
// 125.540 us; speedup vs baseline: 1.6173x; 1.2196x over previous
//
#include <hip/hip_runtime.h>

typedef __attribute__((ext_vector_type(4))) float f32x4;
typedef __attribute__((ext_vector_type(8))) short bf16x8;

typedef __attribute__((address_space(3))) unsigned char lds_b;
typedef const __attribute__((address_space(1))) unsigned char glb_b;

__device__ __forceinline__ void gload_lds16(const void* g, void* l) {
  __builtin_amdgcn_global_load_lds((glb_b*)g, (lds_b*)l, 16, 0, 0);
}

__device__ __forceinline__ unsigned short f2bf(float f) {
  union { float f; unsigned int u; } v; v.f = f;
  unsigned int r = v.u + 0x7fffu + ((v.u >> 16) & 1u);
  return (unsigned short)(r >> 16);
}

// ---------------------------------------------------------------------------
// prep_A: A_ws[b][n][k*512+m] = bf16(cheb[k][m][n] * att[b][m][n])
// grid (8 m-tiles, 8 n-tiles, 32 b), 256 threads. LDS transpose 64x64 per k.
// ---------------------------------------------------------------------------
__global__ __launch_bounds__(256) void prep_A_k(const float* __restrict__ cheb,
                                                const float* __restrict__ att,
                                                unsigned short* __restrict__ A_ws) {
  __shared__ float tile[64][68];
  const int m0 = blockIdx.x * 64, n0 = blockIdx.y * 64, b = blockIdx.z;
  const int tid = threadIdx.x;
  const int rm = tid >> 2;   // 0..63
  const int c4 = tid & 3;    // 0..3
  for (int k = 0; k < 3; ++k) {
    const float* cp = cheb + ((size_t)(k * 512 + m0 + rm)) * 512 + n0 + c4 * 16;
    const float* ap = att  + ((size_t)(b * 512 + m0 + rm)) * 512 + n0 + c4 * 16;
#pragma unroll
    for (int j = 0; j < 4; ++j) {
      float4 c = *(const float4*)(cp + j * 4);
      float4 a = *(const float4*)(ap + j * 4);
      float4 p; p.x = c.x * a.x; p.y = c.y * a.y; p.z = c.z * a.z; p.w = c.w * a.w;
      *(float4*)&tile[rm][c4 * 16 + j * 4] = p;
    }
    __syncthreads();
    unsigned int pk[8];
#pragma unroll
    for (int i = 0; i < 8; ++i) {
      float v0 = tile[c4 * 16 + 2 * i][rm];
      float v1 = tile[c4 * 16 + 2 * i + 1][rm];
      pk[i] = (unsigned int)f2bf(v0) | ((unsigned int)f2bf(v1) << 16);
    }
    unsigned short* op = A_ws + ((size_t)(b * 512 + n0 + rm)) * 1536 + k * 512 + m0 + c4 * 16;
    uint4 w0; w0.x = pk[0]; w0.y = pk[1]; w0.z = pk[2]; w0.w = pk[3];
    uint4 w1; w1.x = pk[4]; w1.y = pk[5]; w1.z = pk[6]; w1.w = pk[7];
    ((uint4*)op)[0] = w0;
    ((uint4*)op)[1] = w1;
    __syncthreads();
  }
}

// ---------------------------------------------------------------------------
// prep_U_mfma: U_ws[b][k][o*12+t][m] = bf16( sum_f x[b,m,f,t] * Theta[k,f,o] )
// Per (b,t): C[o,m] = Theta_k^T[o,f] . X[f,m]  via mfma_f32_16x16x32_bf16.
// grid (32 m-tiles, 32 b), 256 threads (4 waves; wave = 16 o-rows).
// ---------------------------------------------------------------------------
__global__ __launch_bounds__(256) void prep_U_mfma(const float* __restrict__ x,
                                                   const float* __restrict__ Theta,
                                                   unsigned short* __restrict__ U_ws) {
  __shared__ unsigned short Xl[12 * 16 * 64];  // [t][m][f] swizzled, 24KB
  __shared__ unsigned short Tt[3 * 64 * 64];   // [k][o][f] swizzled, 24KB
  const int m0 = blockIdx.x * 16, b = blockIdx.y;
  const int tid = threadIdx.x;
  const int lane = tid & 63, w = tid >> 6;
  const int c = lane & 15, q = lane >> 4;

  const float* xb = x + ((size_t)(b * 512 + m0)) * 768;
#pragma unroll
  for (int j = 0; j < 12; ++j) {
    int i = tid + j * 256;              // float4 index 0..3071
    int m = i / 192, r = i - m * 192;   // 192 float4 per m-row
    float4 v = *(const float4*)(xb + (size_t)m * 768 + r * 4);
    float vv[4] = {v.x, v.y, v.z, v.w};
#pragma unroll
    for (int jj = 0; jj < 4; ++jj) {
      int e = r * 4 + jj;               // element = f*12 + t
      int f = e / 12, t = e - f * 12;
      int byte = t * 2048 + m * 128 + ((((f >> 3) ^ (m & 7)) << 4) | ((f & 7) << 1));
      *(unsigned short*)((char*)Xl + byte) = f2bf(vv[jj]);
    }
  }
#pragma unroll
  for (int j = 0; j < 12; ++j) {
    int i = tid + j * 256;              // 0..3071
    int k = i >> 10, rr = i & 1023;
    int f = rr >> 4, o0 = (rr & 15) << 2;
    float4 v = *(const float4*)(Theta + ((size_t)(k * 64 + f)) * 64 + o0);
    float vv[4] = {v.x, v.y, v.z, v.w};
#pragma unroll
    for (int jj = 0; jj < 4; ++jj) {
      int o = o0 + jj;
      int byte = k * 8192 + o * 128 + ((((f >> 3) ^ (o & 7)) << 4) | ((f & 7) << 1));
      *(unsigned short*)((char*)Tt + byte) = f2bf(vv[jj]);
    }
  }
  __syncthreads();

  bf16x8 afr[3][2];
#pragma unroll
  for (int k = 0; k < 3; ++k)
#pragma unroll
    for (int h = 0; h < 2; ++h) {
      int g = h * 4 + q;
      afr[k][h] = *(const bf16x8*)((char*)Tt +
                    k * 8192 + (w * 16 + c) * 128 + (((g ^ (c & 7)) << 4)));
    }

  const size_t ub0 = ((size_t)(b * 3)) * 768 * 512 + m0 + c;
  for (int t = 0; t < 12; ++t) {
    bf16x8 bfr[2];
#pragma unroll
    for (int h = 0; h < 2; ++h) {
      int g = h * 4 + q;
      bfr[h] = *(const bf16x8*)((char*)Xl + t * 2048 + c * 128 + (((g ^ (c & 7)) << 4)));
    }
#pragma unroll
    for (int k = 0; k < 3; ++k) {
      f32x4 acc = {0.f, 0.f, 0.f, 0.f};
      acc = __builtin_amdgcn_mfma_f32_16x16x32_bf16(afr[k][0], bfr[0], acc, 0, 0, 0);
      acc = __builtin_amdgcn_mfma_f32_16x16x32_bf16(afr[k][1], bfr[1], acc, 0, 0, 0);
      size_t base = ub0 + (size_t)k * 768 * 512 + (size_t)t * 512;
#pragma unroll
      for (int r = 0; r < 4; ++r) {
        int o = w * 16 + q * 4 + r;
        U_ws[base + (size_t)o * 12 * 512] = f2bf(acc[r]);
      }
    }
  }
}

// ---------------------------------------------------------------------------
// gemm_k: out[b][n][ot] = relu( sum_{km} A_ws[b][n][km] * U_ws[b][k][ot][m] )
// 128x128 tile, BK=64, 4 waves (2x2), mfma_f32_16x16x32_bf16.
// Staging via global_load_lds width=16 (linear LDS dest, pre-swizzled global
// source granule). XCD-aware bijective block remap (768 wgs, 96/XCD) so the
// 6 ot-blocks sharing an A-panel + 4 n-blocks sharing a U-panel co-reside.
// grid 768 x 1D, 256 threads.
// ---------------------------------------------------------------------------
__global__ __launch_bounds__(256) void gemm_k(const unsigned short* __restrict__ A_ws,
                                              const unsigned short* __restrict__ U_ws,
                                              float* __restrict__ out) {
  __shared__ unsigned short At[128 * 64];
  __shared__ unsigned short Bt[128 * 64];
  const int hw = blockIdx.x;
  const int logical = (hw & 7) * 96 + (hw >> 3);
  const int b = logical / 24;
  const int rem = logical - b * 24;
  const int nb = (rem / 6) * 128;
  const int otb = (rem % 6) * 128;

  const int tid = threadIdx.x;
  const int lane = tid & 63, w = tid >> 6;
  const int wr = w >> 1, wc = w & 1;
  const int q = lane >> 4;   // 0..3
  const int c = lane & 15;   // 0..15

  // staging geometry: per issue i, wave w covers rows i*32+w*8 .. +7
  const int rl = lane >> 3;            // row within 8-row group (== row&7)
  const int gsrc = (lane & 7) ^ rl;    // pre-swizzled source granule
  f32x4 acc[4][4] = {};

  const unsigned short* aRow = A_ws + ((size_t)(b * 512 + nb + w * 8 + rl)) * 1536 + gsrc * 8;
  const int ldsRowBase = w * 8 * 64;   // ushort index of wave's row-group

  for (int kt = 0; kt < 24; ++kt) {
    const int k = kt >> 3;
    const int m0k = (kt & 7) << 6;
    const unsigned short* uRow =
        U_ws + ((size_t)((b * 3 + k) * 768 + otb + w * 8 + rl)) * 512 + m0k + gsrc * 8;
#pragma unroll
    for (int i = 0; i < 4; ++i) {
      gload_lds16(aRow + (size_t)(i * 32) * 1536 + kt * 64, &At[ldsRowBase + i * 32 * 64]);
      gload_lds16(uRow + (size_t)(i * 32) * 512,            &Bt[ldsRowBase + i * 32 * 64]);
    }
    __syncthreads();   // drains vmcnt: staging complete
#pragma unroll
    for (int h = 0; h < 2; ++h) {
      bf16x8 af[4], bfv[4];
#pragma unroll
      for (int mi = 0; mi < 4; ++mi) {
        int row = wr * 64 + mi * 16 + c;
        af[mi] = *(const bf16x8*)&At[row * 64 + (((h * 4 + q) ^ (row & 7)) << 3)];
      }
#pragma unroll
      for (int ni = 0; ni < 4; ++ni) {
        int row = wc * 64 + ni * 16 + c;
        bfv[ni] = *(const bf16x8*)&Bt[row * 64 + (((h * 4 + q) ^ (row & 7)) << 3)];
      }
#pragma unroll
      for (int mi = 0; mi < 4; ++mi)
#pragma unroll
        for (int ni = 0; ni < 4; ++ni)
          acc[mi][ni] = __builtin_amdgcn_mfma_f32_16x16x32_bf16(af[mi], bfv[ni], acc[mi][ni], 0, 0, 0);
    }
    __syncthreads();   // all waves done reading before next stage overwrites
  }
#pragma unroll
  for (int mi = 0; mi < 4; ++mi) {
#pragma unroll
    for (int r = 0; r < 4; ++r) {
      int n = nb + wr * 64 + mi * 16 + q * 4 + r;
      float* orow = out + ((size_t)(b * 512 + n)) * 768 + otb + wc * 64 + c;
#pragma unroll
      for (int ni = 0; ni < 4; ++ni)
        orow[ni * 16] = fmaxf(acc[mi][ni][r], 0.f);
    }
  }
}

// ---------------------------------------------------------------------------
// Fallback (exact fp32, no workspace): grid (512 n, 32 b), 256 threads.
// ---------------------------------------------------------------------------
__global__ __launch_bounds__(256) void fallback_k(const float* __restrict__ x,
                                                  const float* __restrict__ cheb,
                                                  const float* __restrict__ att,
                                                  const float* __restrict__ Theta,
                                                  float* __restrict__ out) {
  __shared__ float wsm[3][512];
  __shared__ float z[3][768];
  const int n = blockIdx.x, b = blockIdx.y;
  const int tid = threadIdx.x;
  for (int i = tid; i < 1536; i += 256) {
    int k = i >> 9, m = i & 511;
    wsm[k][m] = cheb[((size_t)(k * 512 + m)) * 512 + n] * att[((size_t)(b * 512 + m)) * 512 + n];
  }
  __syncthreads();
  float a0[3] = {0.f, 0.f, 0.f}, a1[3] = {0.f, 0.f, 0.f}, a2[3] = {0.f, 0.f, 0.f};
  const float* xb = x + (size_t)b * 512 * 768;
  for (int m = 0; m < 512; ++m) {
    float w0 = wsm[0][m], w1 = wsm[1][m], w2 = wsm[2][m];
    float x0 = xb[(size_t)m * 768 + tid];
    float x1 = xb[(size_t)m * 768 + tid + 256];
    float x2 = xb[(size_t)m * 768 + tid + 512];
    a0[0] += w0 * x0; a0[1] += w1 * x0; a0[2] += w2 * x0;
    a1[0] += w0 * x1; a1[1] += w1 * x1; a1[2] += w2 * x1;
    a2[0] += w0 * x2; a2[1] += w1 * x2; a2[2] += w2 * x2;
  }
#pragma unroll
  for (int k = 0; k < 3; ++k) {
    z[k][tid] = a0[k]; z[k][tid + 256] = a1[k]; z[k][tid + 512] = a2[k];
  }
  __syncthreads();
#pragma unroll
  for (int j = 0; j < 3; ++j) {
    int ot = tid + j * 256;
    int o = ot / 12, t = ot - o * 12;
    float s = 0.f;
    for (int k = 0; k < 3; ++k)
#pragma unroll
      for (int f = 0; f < 64; ++f)
        s += z[k][f * 12 + t] * Theta[((size_t)(k * 64 + f)) * 64 + o];
    out[((size_t)(b * 512 + n)) * 768 + ot] = fmaxf(s, 0.f);
  }
}

extern "C" void kernel_launch(void* const* d_in, const int* in_sizes, int n_in,
                              void* d_out, int out_size, void* d_ws, size_t ws_size,
                              hipStream_t stream) {
  const float* x     = (const float*)d_in[0];  // (32,512,64,12)
  const float* cheb  = (const float*)d_in[1];  // (3,512,512)
  const float* att   = (const float*)d_in[2];  // (32,512,512)
  const float* Theta = (const float*)d_in[3];  // (3,64,64)
  float* out = (float*)d_out;                  // (32,512,64,12)

  const size_t needA = (size_t)32 * 512 * 1536 * 2;       // 50,331,648
  const size_t needU = (size_t)32 * 3 * 768 * 512 * 2;    // 75,497,472

  if (ws_size >= needA + needU) {
    unsigned short* A_ws = (unsigned short*)d_ws;
    unsigned short* U_ws = (unsigned short*)((char*)d_ws + needA);
    prep_A_k<<<dim3(8, 8, 32), 256, 0, stream>>>(cheb, att, A_ws);
    prep_U_mfma<<<dim3(32, 32), 256, 0, stream>>>(x, Theta, U_ws);
    gemm_k<<<dim3(768), 256, 0, stream>>>(A_ws, U_ws, out);
  } else {
    fallback_k<<<dim3(512, 32), 256, 0, stream>>>(x, cheb, att, Theta, out);
  }
}

// Round 4
// 118.486 us; speedup vs baseline: 1.7136x; 1.0595x over previous
//
#include <hip/hip_runtime.h>

typedef __attribute__((ext_vector_type(4))) float f32x4;
typedef __attribute__((ext_vector_type(8))) short bf16x8;

typedef __attribute__((address_space(3))) unsigned char lds_b;
typedef const __attribute__((address_space(1))) unsigned char glb_b;

__device__ __forceinline__ void gload_lds16(const void* g, void* l) {
  __builtin_amdgcn_global_load_lds((glb_b*)g, (lds_b*)l, 16, 0, 0);
}

__device__ __forceinline__ unsigned short f2bf(float f) {
  union { float f; unsigned int u; } v; v.f = f;
  unsigned int r = v.u + 0x7fffu + ((v.u >> 16) & 1u);
  return (unsigned short)(r >> 16);
}

// ---------------------------------------------------------------------------
// prep_A: A_ws[b][n][k*512+m] = bf16(cheb[k][m][n] * att[b][m][n])
// grid (8 m-tiles, 8 n-tiles, 32 b), 256 threads. LDS transpose 64x64 per k.
// Block (0,0,0) additionally writes Tg = swizzled bf16 Theta^T (24 KB) for
// prep_U's fragment loads (stream-ordered: prep_U launches after prep_A).
// ---------------------------------------------------------------------------
__global__ __launch_bounds__(256) void prep_A_k(const float* __restrict__ cheb,
                                                const float* __restrict__ att,
                                                const float* __restrict__ Theta,
                                                unsigned short* __restrict__ A_ws,
                                                unsigned short* __restrict__ Tg) {
  __shared__ float tile[64][68];
  const int m0 = blockIdx.x * 64, n0 = blockIdx.y * 64, b = blockIdx.z;
  const int tid = threadIdx.x;
  const int rm = tid >> 2;   // 0..63
  const int c4 = tid & 3;    // 0..3
  for (int k = 0; k < 3; ++k) {
    const float* cp = cheb + ((size_t)(k * 512 + m0 + rm)) * 512 + n0 + c4 * 16;
    const float* ap = att  + ((size_t)(b * 512 + m0 + rm)) * 512 + n0 + c4 * 16;
#pragma unroll
    for (int j = 0; j < 4; ++j) {
      float4 c = *(const float4*)(cp + j * 4);
      float4 a = *(const float4*)(ap + j * 4);
      float4 p; p.x = c.x * a.x; p.y = c.y * a.y; p.z = c.z * a.z; p.w = c.w * a.w;
      *(float4*)&tile[rm][c4 * 16 + j * 4] = p;
    }
    __syncthreads();
    unsigned int pk[8];
#pragma unroll
    for (int i = 0; i < 8; ++i) {
      float v0 = tile[c4 * 16 + 2 * i][rm];
      float v1 = tile[c4 * 16 + 2 * i + 1][rm];
      pk[i] = (unsigned int)f2bf(v0) | ((unsigned int)f2bf(v1) << 16);
    }
    unsigned short* op = A_ws + ((size_t)(b * 512 + n0 + rm)) * 1536 + k * 512 + m0 + c4 * 16;
    uint4 w0; w0.x = pk[0]; w0.y = pk[1]; w0.z = pk[2]; w0.w = pk[3];
    uint4 w1; w1.x = pk[4]; w1.y = pk[5]; w1.z = pk[6]; w1.w = pk[7];
    ((uint4*)op)[0] = w0;
    ((uint4*)op)[1] = w1;
    __syncthreads();
  }
  // ---- one block writes Tg[k][o][f] (swizzled) = bf16(Theta[k][f][o]) ----
  if (blockIdx.x == 0 && blockIdx.y == 0 && blockIdx.z == 0) {
#pragma unroll
    for (int j = 0; j < 12; ++j) {
      int i = tid + j * 256;              // 0..3071 float4 index
      int k = i >> 10, rr = i & 1023;
      int f = rr >> 4, o0 = (rr & 15) << 2;
      float4 v = *(const float4*)(Theta + ((size_t)(k * 64 + f)) * 64 + o0);
      float vv[4] = {v.x, v.y, v.z, v.w};
#pragma unroll
      for (int jj = 0; jj < 4; ++jj) {
        int o = o0 + jj;
        int byte = k * 8192 + o * 128 + ((((f >> 3) ^ (o & 7)) << 4) | ((f & 7) << 1));
        *(unsigned short*)((char*)Tg + byte) = f2bf(vv[jj]);
      }
    }
  }
}

// ---------------------------------------------------------------------------
// prep_U_mfma: U_ws[b][k][o*12+t][m] = bf16( sum_f x[b,m,f,t] * Theta[k,f,o] )
// Per (b,t): C[o,m] = Theta_k^T[o,f] . X[f,m]  via mfma_f32_16x16x32_bf16.
// Theta fragments loaded directly from precomputed Tg (coalesced 16B, L2-hot).
// LDS = Xl only (24 KB) -> 6 blocks/CU, all 1024 blocks co-resident.
// grid (32 m-tiles, 32 b), 256 threads (4 waves; wave = 16 o-rows).
// ---------------------------------------------------------------------------
__global__ __launch_bounds__(256) void prep_U_mfma(const float* __restrict__ x,
                                                   const unsigned short* __restrict__ Tg,
                                                   unsigned short* __restrict__ U_ws) {
  __shared__ unsigned short Xl[12 * 16 * 64];  // [t][m][f] swizzled, 24KB
  const int m0 = blockIdx.x * 16, b = blockIdx.y;
  const int tid = threadIdx.x;
  const int lane = tid & 63, w = tid >> 6;
  const int c = lane & 15, q = lane >> 4;

  // ---- Theta fragments: 6 coalesced 16B loads, issued early ----
  bf16x8 afr[3][2];
#pragma unroll
  for (int k = 0; k < 3; ++k)
#pragma unroll
    for (int h = 0; h < 2; ++h) {
      int g = h * 4 + q;
      afr[k][h] = *(const bf16x8*)((const char*)Tg +
                    k * 8192 + (w * 16 + c) * 128 + (((g ^ (c & 7)) << 4)));
    }

  // ---- stage Xl: x[b, m0..m0+15, :, :] = 12288 floats, coalesced float4 ----
  const float* xb = x + ((size_t)(b * 512 + m0)) * 768;
#pragma unroll
  for (int j = 0; j < 12; ++j) {
    int i = tid + j * 256;              // float4 index 0..3071
    int m = i / 192, r = i - m * 192;   // 192 float4 per m-row
    float4 v = *(const float4*)(xb + (size_t)m * 768 + r * 4);
    float vv[4] = {v.x, v.y, v.z, v.w};
#pragma unroll
    for (int jj = 0; jj < 4; ++jj) {
      int e = r * 4 + jj;               // element = f*12 + t
      int f = e / 12, t = e - f * 12;
      int byte = t * 2048 + m * 128 + ((((f >> 3) ^ (m & 7)) << 4) | ((f & 7) << 1));
      *(unsigned short*)((char*)Xl + byte) = f2bf(vv[jj]);
    }
  }
  __syncthreads();

  // ---- main loop: per t, 2 b128 B-frag reads + 6 MFMA + 12 stores ----
  const size_t ub0 = ((size_t)(b * 3)) * 768 * 512 + m0 + c;
  for (int t = 0; t < 12; ++t) {
    bf16x8 bfr[2];
#pragma unroll
    for (int h = 0; h < 2; ++h) {
      int g = h * 4 + q;
      bfr[h] = *(const bf16x8*)((char*)Xl + t * 2048 + c * 128 + (((g ^ (c & 7)) << 4)));
    }
#pragma unroll
    for (int k = 0; k < 3; ++k) {
      f32x4 acc = {0.f, 0.f, 0.f, 0.f};
      acc = __builtin_amdgcn_mfma_f32_16x16x32_bf16(afr[k][0], bfr[0], acc, 0, 0, 0);
      acc = __builtin_amdgcn_mfma_f32_16x16x32_bf16(afr[k][1], bfr[1], acc, 0, 0, 0);
      size_t base = ub0 + (size_t)k * 768 * 512 + (size_t)t * 512;
#pragma unroll
      for (int r = 0; r < 4; ++r) {
        int o = w * 16 + q * 4 + r;
        U_ws[base + (size_t)o * 12 * 512] = f2bf(acc[r]);
      }
    }
  }
}

// ---------------------------------------------------------------------------
// gemm_k: out[b][n][ot] = relu( sum_{km} A_ws[b][n][km] * U_ws[b][k][ot][m] )
// 128x128 tile, BK=64, 4 waves (2x2), mfma_f32_16x16x32_bf16.
// global_load_lds width=16 staging; XCD-aware bijective remap (768 wgs).
// ---------------------------------------------------------------------------
__global__ __launch_bounds__(256) void gemm_k(const unsigned short* __restrict__ A_ws,
                                              const unsigned short* __restrict__ U_ws,
                                              float* __restrict__ out) {
  __shared__ unsigned short At[128 * 64];
  __shared__ unsigned short Bt[128 * 64];
  const int hw = blockIdx.x;
  const int logical = (hw & 7) * 96 + (hw >> 3);
  const int b = logical / 24;
  const int rem = logical - b * 24;
  const int nb = (rem / 6) * 128;
  const int otb = (rem % 6) * 128;

  const int tid = threadIdx.x;
  const int lane = tid & 63, w = tid >> 6;
  const int wr = w >> 1, wc = w & 1;
  const int q = lane >> 4;   // 0..3
  const int c = lane & 15;   // 0..15

  const int rl = lane >> 3;            // row within 8-row group (== row&7)
  const int gsrc = (lane & 7) ^ rl;    // pre-swizzled source granule
  f32x4 acc[4][4] = {};

  const unsigned short* aRow = A_ws + ((size_t)(b * 512 + nb + w * 8 + rl)) * 1536 + gsrc * 8;
  const int ldsRowBase = w * 8 * 64;

  for (int kt = 0; kt < 24; ++kt) {
    const int k = kt >> 3;
    const int m0k = (kt & 7) << 6;
    const unsigned short* uRow =
        U_ws + ((size_t)((b * 3 + k) * 768 + otb + w * 8 + rl)) * 512 + m0k + gsrc * 8;
#pragma unroll
    for (int i = 0; i < 4; ++i) {
      gload_lds16(aRow + (size_t)(i * 32) * 1536 + kt * 64, &At[ldsRowBase + i * 32 * 64]);
      gload_lds16(uRow + (size_t)(i * 32) * 512,            &Bt[ldsRowBase + i * 32 * 64]);
    }
    __syncthreads();
#pragma unroll
    for (int h = 0; h < 2; ++h) {
      bf16x8 af[4], bfv[4];
#pragma unroll
      for (int mi = 0; mi < 4; ++mi) {
        int row = wr * 64 + mi * 16 + c;
        af[mi] = *(const bf16x8*)&At[row * 64 + (((h * 4 + q) ^ (row & 7)) << 3)];
      }
#pragma unroll
      for (int ni = 0; ni < 4; ++ni) {
        int row = wc * 64 + ni * 16 + c;
        bfv[ni] = *(const bf16x8*)&Bt[row * 64 + (((h * 4 + q) ^ (row & 7)) << 3)];
      }
#pragma unroll
      for (int mi = 0; mi < 4; ++mi)
#pragma unroll
        for (int ni = 0; ni < 4; ++ni)
          acc[mi][ni] = __builtin_amdgcn_mfma_f32_16x16x32_bf16(af[mi], bfv[ni], acc[mi][ni], 0, 0, 0);
    }
    __syncthreads();
  }
#pragma unroll
  for (int mi = 0; mi < 4; ++mi) {
#pragma unroll
    for (int r = 0; r < 4; ++r) {
      int n = nb + wr * 64 + mi * 16 + q * 4 + r;
      float* orow = out + ((size_t)(b * 512 + n)) * 768 + otb + wc * 64 + c;
#pragma unroll
      for (int ni = 0; ni < 4; ++ni)
        orow[ni * 16] = fmaxf(acc[mi][ni][r], 0.f);
    }
  }
}

// ---------------------------------------------------------------------------
// Fallback (exact fp32, no workspace): grid (512 n, 32 b), 256 threads.
// ---------------------------------------------------------------------------
__global__ __launch_bounds__(256) void fallback_k(const float* __restrict__ x,
                                                  const float* __restrict__ cheb,
                                                  const float* __restrict__ att,
                                                  const float* __restrict__ Theta,
                                                  float* __restrict__ out) {
  __shared__ float wsm[3][512];
  __shared__ float z[3][768];
  const int n = blockIdx.x, b = blockIdx.y;
  const int tid = threadIdx.x;
  for (int i = tid; i < 1536; i += 256) {
    int k = i >> 9, m = i & 511;
    wsm[k][m] = cheb[((size_t)(k * 512 + m)) * 512 + n] * att[((size_t)(b * 512 + m)) * 512 + n];
  }
  __syncthreads();
  float a0[3] = {0.f, 0.f, 0.f}, a1[3] = {0.f, 0.f, 0.f}, a2[3] = {0.f, 0.f, 0.f};
  const float* xb = x + (size_t)b * 512 * 768;
  for (int m = 0; m < 512; ++m) {
    float w0 = wsm[0][m], w1 = wsm[1][m], w2 = wsm[2][m];
    float x0 = xb[(size_t)m * 768 + tid];
    float x1 = xb[(size_t)m * 768 + tid + 256];
    float x2 = xb[(size_t)m * 768 + tid + 512];
    a0[0] += w0 * x0; a0[1] += w1 * x0; a0[2] += w2 * x0;
    a1[0] += w0 * x1; a1[1] += w1 * x1; a1[2] += w2 * x1;
    a2[0] += w0 * x2; a2[1] += w1 * x2; a2[2] += w2 * x2;
  }
#pragma unroll
  for (int k = 0; k < 3; ++k) {
    z[k][tid] = a0[k]; z[k][tid + 256] = a1[k]; z[k][tid + 512] = a2[k];
  }
  __syncthreads();
#pragma unroll
  for (int j = 0; j < 3; ++j) {
    int ot = tid + j * 256;
    int o = ot / 12, t = ot - o * 12;
    float s = 0.f;
    for (int k = 0; k < 3; ++k)
#pragma unroll
      for (int f = 0; f < 64; ++f)
        s += z[k][f * 12 + t] * Theta[((size_t)(k * 64 + f)) * 64 + o];
    out[((size_t)(b * 512 + n)) * 768 + ot] = fmaxf(s, 0.f);
  }
}

extern "C" void kernel_launch(void* const* d_in, const int* in_sizes, int n_in,
                              void* d_out, int out_size, void* d_ws, size_t ws_size,
                              hipStream_t stream) {
  const float* x     = (const float*)d_in[0];  // (32,512,64,12)
  const float* cheb  = (const float*)d_in[1];  // (3,512,512)
  const float* att   = (const float*)d_in[2];  // (32,512,512)
  const float* Theta = (const float*)d_in[3];  // (3,64,64)
  float* out = (float*)d_out;                  // (32,512,64,12)

  const size_t needA = (size_t)32 * 512 * 1536 * 2;       // 50,331,648
  const size_t needU = (size_t)32 * 3 * 768 * 512 * 2;    // 75,497,472
  const size_t needT = (size_t)3 * 64 * 64 * 2;           // 24,576

  if (ws_size >= needA + needU + needT) {
    unsigned short* A_ws = (unsigned short*)d_ws;
    unsigned short* U_ws = (unsigned short*)((char*)d_ws + needA);
    unsigned short* Tg   = (unsigned short*)((char*)d_ws + needA + needU);
    prep_A_k<<<dim3(8, 8, 32), 256, 0, stream>>>(cheb, att, Theta, A_ws, Tg);
    prep_U_mfma<<<dim3(32, 32), 256, 0, stream>>>(x, Tg, U_ws);
    gemm_k<<<dim3(768), 256, 0, stream>>>(A_ws, U_ws, out);
  } else {
    fallback_k<<<dim3(512, 32), 256, 0, stream>>>(x, cheb, att, Theta, out);
  }
}

// Round 5
// 111.905 us; speedup vs baseline: 1.8144x; 1.0588x over previous
//
#include <hip/hip_runtime.h>

typedef __attribute__((ext_vector_type(4))) float f32x4;
typedef __attribute__((ext_vector_type(8))) short bf16x8;

typedef __attribute__((address_space(3))) unsigned char lds_b;
typedef const __attribute__((address_space(1))) unsigned char glb_b;

__device__ __forceinline__ void gload_lds16(const void* g, void* l) {
  __builtin_amdgcn_global_load_lds((glb_b*)g, (lds_b*)l, 16, 0, 0);
}

__device__ __forceinline__ unsigned short f2bf(float f) {
  union { float f; unsigned int u; } v; v.f = f;
  unsigned int r = v.u + 0x7fffu + ((v.u >> 16) & 1u);
  return (unsigned short)(r >> 16);
}

// ---------------------------------------------------------------------------
// theta_prep: Tg[k][o][f] (XOR-swizzled) = bf16(Theta[k][f][o]). grid 1.
// ---------------------------------------------------------------------------
__global__ __launch_bounds__(256) void theta_prep_k(const float* __restrict__ Theta,
                                                    unsigned short* __restrict__ Tg) {
  const int tid = threadIdx.x;
#pragma unroll
  for (int j = 0; j < 12; ++j) {
    int i = tid + j * 256;              // 0..3071 float4 index
    int k = i >> 10, rr = i & 1023;
    int f = rr >> 4, o0 = (rr & 15) << 2;
    float4 v = *(const float4*)(Theta + ((size_t)(k * 64 + f)) * 64 + o0);
    float vv[4] = {v.x, v.y, v.z, v.w};
#pragma unroll
    for (int jj = 0; jj < 4; ++jj) {
      int o = o0 + jj;
      int byte = k * 8192 + o * 128 + ((((f >> 3) ^ (o & 7)) << 4) | ((f & 7) << 1));
      *(unsigned short*)((char*)Tg + byte) = f2bf(vv[jj]);
    }
  }
}

// ---------------------------------------------------------------------------
// prep_fused: blocks [0,1024) = prep_U (launched first, long pole);
//             blocks [1024,3072) = prep_A. One dispatch -> the read-bound
// prep_A work overlaps the store/latency-bound prep_U work.
//
// prep_U m-quad XCD swizzle: the 4 m-tiles completing each 128B U-line are
// mapped to the SAME XCD (hw%8) so one L2 assembles full lines (avoids
// cross-XCD partial-line masked writes to DRAM).
// ---------------------------------------------------------------------------
__global__ __launch_bounds__(256) void prep_fused_k(const float* __restrict__ x,
                                                    const float* __restrict__ cheb,
                                                    const float* __restrict__ att,
                                                    const unsigned short* __restrict__ Tg,
                                                    unsigned short* __restrict__ A_ws,
                                                    unsigned short* __restrict__ U_ws) {
  __shared__ __align__(16) char smem[24576];
  const int bid = blockIdx.x;
  const int tid = threadIdx.x;

  if (bid < 1024) {
    // ================= prep_U part =================
    unsigned short* Xl = (unsigned short*)smem;  // [t][m][f] swizzled, 24KB
    const int xcd = bid & 7, tt = bid >> 3;      // assume hw round-robin on 8 XCDs
    const int l = (tt & ~3) * 8 + xcd * 4 + (tt & 3);  // bijective [0,1024)
    const int b = l >> 5, mt = l & 31;           // line-group (b, mt>>2) on one XCD
    const int m0 = mt * 16;
    const int lane = tid & 63, w = tid >> 6;
    const int c = lane & 15, q = lane >> 4;

    // Theta fragments: 6 coalesced 16B loads (Tg is L2-hot, written by pre-kernel)
    bf16x8 afr[3][2];
#pragma unroll
    for (int k = 0; k < 3; ++k)
#pragma unroll
      for (int h = 0; h < 2; ++h) {
        int g = h * 4 + q;
        afr[k][h] = *(const bf16x8*)((const char*)Tg +
                      k * 8192 + (w * 16 + c) * 128 + (((g ^ (c & 7)) << 4)));
      }

    // stage Xl: x[b, m0..m0+15, :, :], coalesced float4
    const float* xb = x + ((size_t)(b * 512 + m0)) * 768;
#pragma unroll
    for (int j = 0; j < 12; ++j) {
      int i = tid + j * 256;
      int m = i / 192, r = i - m * 192;
      float4 v = *(const float4*)(xb + (size_t)m * 768 + r * 4);
      float vv[4] = {v.x, v.y, v.z, v.w};
#pragma unroll
      for (int jj = 0; jj < 4; ++jj) {
        int e = r * 4 + jj;               // element = f*12 + t
        int f = e / 12, t = e - f * 12;
        int byte = t * 2048 + m * 128 + ((((f >> 3) ^ (m & 7)) << 4) | ((f & 7) << 1));
        *(unsigned short*)((char*)Xl + byte) = f2bf(vv[jj]);
      }
    }
    __syncthreads();

    const size_t ub0 = ((size_t)(b * 3)) * 768 * 512 + m0 + c;
    for (int t = 0; t < 12; ++t) {
      bf16x8 bfr[2];
#pragma unroll
      for (int h = 0; h < 2; ++h) {
        int g = h * 4 + q;
        bfr[h] = *(const bf16x8*)((char*)Xl + t * 2048 + c * 128 + (((g ^ (c & 7)) << 4)));
      }
#pragma unroll
      for (int k = 0; k < 3; ++k) {
        f32x4 acc = {0.f, 0.f, 0.f, 0.f};
        acc = __builtin_amdgcn_mfma_f32_16x16x32_bf16(afr[k][0], bfr[0], acc, 0, 0, 0);
        acc = __builtin_amdgcn_mfma_f32_16x16x32_bf16(afr[k][1], bfr[1], acc, 0, 0, 0);
        size_t base = ub0 + (size_t)k * 768 * 512 + (size_t)t * 512;
#pragma unroll
        for (int r = 0; r < 4; ++r) {
          int o = w * 16 + q * 4 + r;
          U_ws[base + (size_t)o * 12 * 512] = f2bf(acc[r]);
        }
      }
    }
  } else {
    // ================= prep_A part =================
    float (*tile)[68] = (float(*)[68])smem;      // 64x68 fp32, 17.4KB
    const int id = bid - 1024;
    const int m0 = (id & 7) * 64, n0 = ((id >> 3) & 7) * 64, b = id >> 6;
    const int rm = tid >> 2;   // 0..63
    const int c4 = tid & 3;    // 0..3
    for (int k = 0; k < 3; ++k) {
      const float* cp = cheb + ((size_t)(k * 512 + m0 + rm)) * 512 + n0 + c4 * 16;
      const float* ap = att  + ((size_t)(b * 512 + m0 + rm)) * 512 + n0 + c4 * 16;
#pragma unroll
      for (int j = 0; j < 4; ++j) {
        float4 cc = *(const float4*)(cp + j * 4);
        float4 aa = *(const float4*)(ap + j * 4);
        float4 p; p.x = cc.x * aa.x; p.y = cc.y * aa.y; p.z = cc.z * aa.z; p.w = cc.w * aa.w;
        *(float4*)&tile[rm][c4 * 16 + j * 4] = p;
      }
      __syncthreads();
      unsigned int pk[8];
#pragma unroll
      for (int i = 0; i < 8; ++i) {
        float v0 = tile[c4 * 16 + 2 * i][rm];
        float v1 = tile[c4 * 16 + 2 * i + 1][rm];
        pk[i] = (unsigned int)f2bf(v0) | ((unsigned int)f2bf(v1) << 16);
      }
      unsigned short* op = A_ws + ((size_t)(b * 512 + n0 + rm)) * 1536 + k * 512 + m0 + c4 * 16;
      uint4 w0; w0.x = pk[0]; w0.y = pk[1]; w0.z = pk[2]; w0.w = pk[3];
      uint4 w1; w1.x = pk[4]; w1.y = pk[5]; w1.z = pk[6]; w1.w = pk[7];
      ((uint4*)op)[0] = w0;
      ((uint4*)op)[1] = w1;
      __syncthreads();
    }
  }
}

// ---------------------------------------------------------------------------
// gemm_k: out[b][n][ot] = relu( sum_{km} A_ws[b][n][km] * U_ws[b][k][ot][m] )
// 128x128 tile, BK=64, 4 waves (2x2), mfma_f32_16x16x32_bf16.
// global_load_lds width=16 staging; XCD-aware bijective remap (768 wgs).
// ---------------------------------------------------------------------------
__global__ __launch_bounds__(256) void gemm_k(const unsigned short* __restrict__ A_ws,
                                              const unsigned short* __restrict__ U_ws,
                                              float* __restrict__ out) {
  __shared__ unsigned short At[128 * 64];
  __shared__ unsigned short Bt[128 * 64];
  const int hw = blockIdx.x;
  const int logical = (hw & 7) * 96 + (hw >> 3);
  const int b = logical / 24;
  const int rem = logical - b * 24;
  const int nb = (rem / 6) * 128;
  const int otb = (rem % 6) * 128;

  const int tid = threadIdx.x;
  const int lane = tid & 63, w = tid >> 6;
  const int wr = w >> 1, wc = w & 1;
  const int q = lane >> 4;   // 0..3
  const int c = lane & 15;   // 0..15

  const int rl = lane >> 3;            // row within 8-row group (== row&7)
  const int gsrc = (lane & 7) ^ rl;    // pre-swizzled source granule
  f32x4 acc[4][4] = {};

  const unsigned short* aRow = A_ws + ((size_t)(b * 512 + nb + w * 8 + rl)) * 1536 + gsrc * 8;
  const int ldsRowBase = w * 8 * 64;

  for (int kt = 0; kt < 24; ++kt) {
    const int k = kt >> 3;
    const int m0k = (kt & 7) << 6;
    const unsigned short* uRow =
        U_ws + ((size_t)((b * 3 + k) * 768 + otb + w * 8 + rl)) * 512 + m0k + gsrc * 8;
#pragma unroll
    for (int i = 0; i < 4; ++i) {
      gload_lds16(aRow + (size_t)(i * 32) * 1536 + kt * 64, &At[ldsRowBase + i * 32 * 64]);
      gload_lds16(uRow + (size_t)(i * 32) * 512,            &Bt[ldsRowBase + i * 32 * 64]);
    }
    __syncthreads();
#pragma unroll
    for (int h = 0; h < 2; ++h) {
      bf16x8 af[4], bfv[4];
#pragma unroll
      for (int mi = 0; mi < 4; ++mi) {
        int row = wr * 64 + mi * 16 + c;
        af[mi] = *(const bf16x8*)&At[row * 64 + (((h * 4 + q) ^ (row & 7)) << 3)];
      }
#pragma unroll
      for (int ni = 0; ni < 4; ++ni) {
        int row = wc * 64 + ni * 16 + c;
        bfv[ni] = *(const bf16x8*)&Bt[row * 64 + (((h * 4 + q) ^ (row & 7)) << 3)];
      }
#pragma unroll
      for (int mi = 0; mi < 4; ++mi)
#pragma unroll
        for (int ni = 0; ni < 4; ++ni)
          acc[mi][ni] = __builtin_amdgcn_mfma_f32_16x16x32_bf16(af[mi], bfv[ni], acc[mi][ni], 0, 0, 0);
    }
    __syncthreads();
  }
#pragma unroll
  for (int mi = 0; mi < 4; ++mi) {
#pragma unroll
    for (int r = 0; r < 4; ++r) {
      int n = nb + wr * 64 + mi * 16 + q * 4 + r;
      float* orow = out + ((size_t)(b * 512 + n)) * 768 + otb + wc * 64 + c;
#pragma unroll
      for (int ni = 0; ni < 4; ++ni)
        orow[ni * 16] = fmaxf(acc[mi][ni][r], 0.f);
    }
  }
}

// ---------------------------------------------------------------------------
// Fallback (exact fp32, no workspace): grid (512 n, 32 b), 256 threads.
// ---------------------------------------------------------------------------
__global__ __launch_bounds__(256) void fallback_k(const float* __restrict__ x,
                                                  const float* __restrict__ cheb,
                                                  const float* __restrict__ att,
                                                  const float* __restrict__ Theta,
                                                  float* __restrict__ out) {
  __shared__ float wsm[3][512];
  __shared__ float z[3][768];
  const int n = blockIdx.x, b = blockIdx.y;
  const int tid = threadIdx.x;
  for (int i = tid; i < 1536; i += 256) {
    int k = i >> 9, m = i & 511;
    wsm[k][m] = cheb[((size_t)(k * 512 + m)) * 512 + n] * att[((size_t)(b * 512 + m)) * 512 + n];
  }
  __syncthreads();
  float a0[3] = {0.f, 0.f, 0.f}, a1[3] = {0.f, 0.f, 0.f}, a2[3] = {0.f, 0.f, 0.f};
  const float* xb = x + (size_t)b * 512 * 768;
  for (int m = 0; m < 512; ++m) {
    float w0 = wsm[0][m], w1 = wsm[1][m], w2 = wsm[2][m];
    float x0 = xb[(size_t)m * 768 + tid];
    float x1 = xb[(size_t)m * 768 + tid + 256];
    float x2 = xb[(size_t)m * 768 + tid + 512];
    a0[0] += w0 * x0; a0[1] += w1 * x0; a0[2] += w2 * x0;
    a1[0] += w0 * x1; a1[1] += w1 * x1; a1[2] += w2 * x1;
    a2[0] += w0 * x2; a2[1] += w1 * x2; a2[2] += w2 * x2;
  }
#pragma unroll
  for (int k = 0; k < 3; ++k) {
    z[k][tid] = a0[k]; z[k][tid + 256] = a1[k]; z[k][tid + 512] = a2[k];
  }
  __syncthreads();
#pragma unroll
  for (int j = 0; j < 3; ++j) {
    int ot = tid + j * 256;
    int o = ot / 12, t = ot - o * 12;
    float s = 0.f;
    for (int k = 0; k < 3; ++k)
#pragma unroll
      for (int f = 0; f < 64; ++f)
        s += z[k][f * 12 + t] * Theta[((size_t)(k * 64 + f)) * 64 + o];
    out[((size_t)(b * 512 + n)) * 768 + ot] = fmaxf(s, 0.f);
  }
}

extern "C" void kernel_launch(void* const* d_in, const int* in_sizes, int n_in,
                              void* d_out, int out_size, void* d_ws, size_t ws_size,
                              hipStream_t stream) {
  const float* x     = (const float*)d_in[0];  // (32,512,64,12)
  const float* cheb  = (const float*)d_in[1];  // (3,512,512)
  const float* att   = (const float*)d_in[2];  // (32,512,512)
  const float* Theta = (const float*)d_in[3];  // (3,64,64)
  float* out = (float*)d_out;                  // (32,512,64,12)

  const size_t needA = (size_t)32 * 512 * 1536 * 2;       // 50,331,648
  const size_t needU = (size_t)32 * 3 * 768 * 512 * 2;    // 75,497,472
  const size_t needT = (size_t)3 * 64 * 64 * 2;           // 24,576

  if (ws_size >= needA + needU + needT) {
    unsigned short* A_ws = (unsigned short*)d_ws;
    unsigned short* U_ws = (unsigned short*)((char*)d_ws + needA);
    unsigned short* Tg   = (unsigned short*)((char*)d_ws + needA + needU);
    theta_prep_k<<<dim3(1), 256, 0, stream>>>(Theta, Tg);
    prep_fused_k<<<dim3(3072), 256, 0, stream>>>(x, cheb, att, Tg, A_ws, U_ws);
    gemm_k<<<dim3(768), 256, 0, stream>>>(A_ws, U_ws, out);
  } else {
    fallback_k<<<dim3(512, 32), 256, 0, stream>>>(x, cheb, att, Theta, out);
  }
}